// Round 4
// baseline (233.599 us; speedup 1.0000x reference)
//
#include <hip/hip_runtime.h>
#include <hip/hip_cooperative_groups.h>

namespace cg = cooperative_groups;

// Problem constants: B=4, H=64, W=64, d=V=O=64, HW=4096
#define HW 4096
#define EPSF 1e-7f

// ws layout (float offsets):
#define WS_S1  0         // [4*64*64]  S1[b,l,j]
#define WS_S2P 16384     // [4*64*64]  S2 partial per l
#define WS_QSP 32768     // [4*64*64]  Qsum partial per l
#define WS_Z   49152     // [4*64*64]  z[b,a,j] (unnormalized by norm)
#define WS_NRM 65536     // [4*64]     norm[b,j]
#define WS_IN2 65792     // [4*64]     1/norm^2
#define WS_G   66048     // [4*64*64]  G = z^T z
#define WS_P   82432     // [4*64*64]  P = z^T w
#define WS_ZO  98816     // [4*64*64]  Zo (post-relu)
#define WS_Q   115200    // [4*4096*64] Q

struct SMemA { float red[3][4][64]; float abc[3][64]; };
struct SMemB { float ra[4][64]; float rb[4][64]; float rc[4][64]; };
struct SMemC { float gred[4][64]; float pred[4][64]; float nred[4][64]; };
struct SMemD { float ghat[64]; float red[4][64]; };
struct SMemF { float qs[64][65]; float zo[64][68]; };
union SMemU { SMemA a; SMemB b; SMemC c; SMemD d; SMemF f; };

__global__ __launch_bounds__(256) void fused_all(const float* __restrict__ X,
                                                 const float* __restrict__ Wm,
                                                 const float* __restrict__ var,
                                                 const float* __restrict__ weight,
                                                 float* __restrict__ ws,
                                                 float* __restrict__ out) {
    cg::grid_group grid = cg::this_grid();
    __shared__ SMemU sm;
    const int b  = blockIdx.x >> 6;
    const int s  = blockIdx.x & 63;   // l / h / v / tile depending on phase
    const int w4 = threadIdx.x >> 6;  // wave 0..3
    const int j  = threadIdx.x & 63;  // lane

    // ---------------- Phase A: per (b,l). ABC + Q rows + S1/S2p/Qsp ----------
    {
        float invr[16], wivr[16];
        float a = 0.f, bq = 0.f, c = 0.f;
#pragma unroll
        for (int k = 0; k < 16; k++) {
            int i = w4 * 16 + k;
            float v  = var[i * 64 + j];
            float wv = Wm[i * 64 + j];
            float iv = 1.0f / v;
            invr[k] = iv;
            wivr[k] = wv * iv;
            float iv2 = iv * iv;
            a += iv2; bq += wv * iv2; c += wv * wv * iv2;
        }
        sm.a.red[0][w4][j] = a; sm.a.red[1][w4][j] = bq; sm.a.red[2][w4][j] = c;
        __syncthreads();
        if (threadIdx.x < 64) {
            sm.a.abc[0][j] = sm.a.red[0][0][j] + sm.a.red[0][1][j] + sm.a.red[0][2][j] + sm.a.red[0][3][j];
            sm.a.abc[1][j] = sm.a.red[1][0][j] + sm.a.red[1][1][j] + sm.a.red[1][2][j] + sm.a.red[1][3][j];
            sm.a.abc[2][j] = sm.a.red[2][0][j] + sm.a.red[2][1][j] + sm.a.red[2][2][j] + sm.a.red[2][3][j];
        }
        __syncthreads();
        float Aj = sm.a.abc[0][j], Bj = sm.a.abc[1][j], Cj = sm.a.abc[2][j];

        float s1 = 0.f, s2 = 0.f, qsum = 0.f;
#pragma unroll
        for (int k = 0; k < 16; k++) {
            int i = w4 * 16 + k;
            int n = s * 64 + i;
            float x = X[((b * HW) + n) * 64 + j];
            float q = fmaf(fmaf(Aj, x, -2.0f * Bj), x, Cj);
            float m = q;
            for (int off = 1; off < 64; off <<= 1) m = fminf(m, __shfl_xor(m, off));
            float e = __expf(-0.5f * (q - m));
            float sum = e;
            for (int off = 1; off < 64; off <<= 1) sum += __shfl_xor(sum, off);
            float Qv = e / sum;
            ws[WS_Q + ((size_t)(b * HW) + n) * 64 + j] = Qv;
            s1 = fmaf(invr[k], Qv, s1);
            s2 = fmaf(wivr[k], Qv, s2);
            qsum += Qv;
        }
        __syncthreads();
        sm.a.red[0][w4][j] = s1; sm.a.red[1][w4][j] = s2; sm.a.red[2][w4][j] = qsum;
        __syncthreads();
        if (threadIdx.x < 64) {
            int idx = (b * 64 + s) * 64 + j;
            ws[WS_S1  + idx] = sm.a.red[0][0][j] + sm.a.red[0][1][j] + sm.a.red[0][2][j] + sm.a.red[0][3][j];
            ws[WS_S2P + idx] = sm.a.red[1][0][j] + sm.a.red[1][1][j] + sm.a.red[1][2][j] + sm.a.red[1][3][j];
            ws[WS_QSP + idx] = sm.a.red[2][0][j] + sm.a.red[2][1][j] + sm.a.red[2][2][j] + sm.a.red[2][3][j];
        }
    }
    __threadfence();
    grid.sync();

    // ---------------- Phase B: per (b,h). z ----------------------------------
    {
        float acc = 0.f, ps2 = 0.f, pqs = 0.f;
#pragma unroll
        for (int k = 0; k < 16; k++) {
            int l = w4 * 16 + k;
            float x = X[((size_t)(b * HW) + s * 64 + l) * 64 + j];
            int idx = (b * 64 + l) * 64 + j;
            acc = fmaf(x, ws[WS_S1 + idx], acc);
            ps2 += ws[WS_S2P + idx];
            pqs += ws[WS_QSP + idx];
        }
        sm.b.ra[w4][j] = acc; sm.b.rb[w4][j] = ps2; sm.b.rc[w4][j] = pqs;
        __syncthreads();
        if (threadIdx.x < 64) {
            float a  = sm.b.ra[0][j] + sm.b.ra[1][j] + sm.b.ra[2][j] + sm.b.ra[3][j];
            float s2 = sm.b.rb[0][j] + sm.b.rb[1][j] + sm.b.rb[2][j] + sm.b.rb[3][j];
            float qs = sm.b.rc[0][j] + sm.b.rc[1][j] + sm.b.rc[2][j] + sm.b.rc[3][j];
            ws[WS_Z + (b * 64 + s) * 64 + j] = (a - s2 + EPSF) / (qs + EPSF);
        }
    }
    __threadfence();
    grid.sync();

    // ---------------- Phase C: per (b,v). G[v,:], P[v,:], nrm ----------------
    {
        float gp = 0.f, pp = 0.f, np = 0.f;
#pragma unroll
        for (int k = 0; k < 16; k++) {
            int d = w4 * 16 + k;
            float zdj = ws[WS_Z + b * 4096 + d * 64 + j];
            float wdj = weight[d * 64 + j];
            float zdv = ws[WS_Z + b * 4096 + d * 64 + s];  // block-uniform broadcast
            gp = fmaf(zdv, zdj, gp);
            pp = fmaf(zdv, wdj, pp);
            np = fmaf(zdj, zdj, np);
        }
        sm.c.gred[w4][j] = gp; sm.c.pred[w4][j] = pp; sm.c.nred[w4][j] = np;
        __syncthreads();
        if (threadIdx.x < 64) {
            float G = sm.c.gred[0][j] + sm.c.gred[1][j] + sm.c.gred[2][j] + sm.c.gred[3][j];
            float P = sm.c.pred[0][j] + sm.c.pred[1][j] + sm.c.pred[2][j] + sm.c.pred[3][j];
            float N = sm.c.nred[0][j] + sm.c.nred[1][j] + sm.c.nred[2][j] + sm.c.nred[3][j];
            ws[WS_G + (b * 64 + s) * 64 + j] = G;
            ws[WS_P + (b * 64 + s) * 64 + j] = P;
            if (s == 0) {
                ws[WS_NRM + b * 64 + j] = N;
                ws[WS_IN2 + b * 64 + j] = 1.0f / (N * N);
            }
        }
    }
    __threadfence();
    grid.sync();

    // ---------------- Phase D: per (b,v). Zo[v,:] ----------------------------
    {
        if (threadIdx.x < 64)
            sm.d.ghat[threadIdx.x] = ws[WS_G + (b * 64 + s) * 64 + threadIdx.x]
                                   * ws[WS_IN2 + b * 64 + threadIdx.x];
        __syncthreads();
        float acc = 0.f;
#pragma unroll
        for (int k = 0; k < 16; k++) {
            int u = w4 * 16 + k;
            acc = fmaf(sm.d.ghat[u], ws[WS_P + (b * 64 + u) * 64 + j], acc);
        }
        sm.d.red[w4][j] = acc;
        __syncthreads();
        if (threadIdx.x < 64) {
            float r = (sm.d.red[0][j] + sm.d.red[1][j] + sm.d.red[2][j] + sm.d.red[3][j])
                      / ws[WS_NRM + b * 64 + s];
            r = r > 0.f ? r : 0.f;
            ws[WS_ZO + (b * 64 + s) * 64 + j] = r;
        }
    }
    __threadfence();
    grid.sync();

    // ---------------- Phase F: per (b,tile). out = Q * Zo --------------------
    {
        int nbase = s * 64;
        int w16 = w4 * 16;
#pragma unroll
        for (int k = 0; k < 16; k++) {
            int idx = threadIdx.x + 256 * k;
            int r = idx >> 6, cc = idx & 63;
            sm.f.qs[r][cc] = ws[WS_Q + ((size_t)(b * HW) + nbase + r) * 64 + cc];
            sm.f.zo[r][cc] = ws[WS_ZO + b * 4096 + idx];
        }
        __syncthreads();
        float acc[16];
#pragma unroll
        for (int k = 0; k < 16; k++) acc[k] = 0.f;
#pragma unroll
        for (int v = 0; v < 64; v++) {
            float qv = sm.f.qs[j][v];
            float4 z0 = *(const float4*)&sm.f.zo[v][w16];
            float4 z1 = *(const float4*)&sm.f.zo[v][w16 + 4];
            float4 z2 = *(const float4*)&sm.f.zo[v][w16 + 8];
            float4 z3 = *(const float4*)&sm.f.zo[v][w16 + 12];
            acc[0]  = fmaf(qv, z0.x, acc[0]);   acc[1]  = fmaf(qv, z0.y, acc[1]);
            acc[2]  = fmaf(qv, z0.z, acc[2]);   acc[3]  = fmaf(qv, z0.w, acc[3]);
            acc[4]  = fmaf(qv, z1.x, acc[4]);   acc[5]  = fmaf(qv, z1.y, acc[5]);
            acc[6]  = fmaf(qv, z1.z, acc[6]);   acc[7]  = fmaf(qv, z1.w, acc[7]);
            acc[8]  = fmaf(qv, z2.x, acc[8]);   acc[9]  = fmaf(qv, z2.y, acc[9]);
            acc[10] = fmaf(qv, z2.z, acc[10]);  acc[11] = fmaf(qv, z2.w, acc[11]);
            acc[12] = fmaf(qv, z3.x, acc[12]);  acc[13] = fmaf(qv, z3.y, acc[13]);
            acc[14] = fmaf(qv, z3.z, acc[14]);  acc[15] = fmaf(qv, z3.w, acc[15]);
        }
#pragma unroll
        for (int k = 0; k < 16; k++) {
            int o = w16 + k;
            out[(size_t)(b * 64 + o) * HW + nbase + j] = acc[k];
        }
    }
}

// ============================================================================
// Fallback path (5 separate kernels) — used only if cooperative launch fails.
// ============================================================================
__global__ __launch_bounds__(256) void kA(const float* __restrict__ X,
                                          const float* __restrict__ Wm,
                                          const float* __restrict__ var,
                                          float* __restrict__ ws) {
    int b = blockIdx.x >> 6;
    int l = blockIdx.x & 63;
    int w = threadIdx.x >> 6;
    int j = threadIdx.x & 63;
    __shared__ float red[3][4][64];
    __shared__ float abc[3][64];
    float invr[16], wivr[16];
    float a = 0.f, bq = 0.f, c = 0.f;
#pragma unroll
    for (int k = 0; k < 16; k++) {
        int i = w * 16 + k;
        float v  = var[i * 64 + j];
        float wv = Wm[i * 64 + j];
        float iv = 1.0f / v;
        invr[k] = iv; wivr[k] = wv * iv;
        float iv2 = iv * iv;
        a += iv2; bq += wv * iv2; c += wv * wv * iv2;
    }
    red[0][w][j] = a; red[1][w][j] = bq; red[2][w][j] = c;
    __syncthreads();
    if (threadIdx.x < 64) {
        abc[0][j] = red[0][0][j] + red[0][1][j] + red[0][2][j] + red[0][3][j];
        abc[1][j] = red[1][0][j] + red[1][1][j] + red[1][2][j] + red[1][3][j];
        abc[2][j] = red[2][0][j] + red[2][1][j] + red[2][2][j] + red[2][3][j];
    }
    __syncthreads();
    float Aj = abc[0][j], Bj = abc[1][j], Cj = abc[2][j];
    float s1 = 0.f, s2 = 0.f, qsum = 0.f;
#pragma unroll
    for (int k = 0; k < 16; k++) {
        int i = w * 16 + k;
        int n = l * 64 + i;
        float x = X[((b * HW) + n) * 64 + j];
        float q = fmaf(fmaf(Aj, x, -2.0f * Bj), x, Cj);
        float m = q;
        for (int off = 1; off < 64; off <<= 1) m = fminf(m, __shfl_xor(m, off));
        float e = __expf(-0.5f * (q - m));
        float sum = e;
        for (int off = 1; off < 64; off <<= 1) sum += __shfl_xor(sum, off);
        float Qv = e / sum;
        ws[WS_Q + ((size_t)(b * HW) + n) * 64 + j] = Qv;
        s1 = fmaf(invr[k], Qv, s1);
        s2 = fmaf(wivr[k], Qv, s2);
        qsum += Qv;
    }
    __syncthreads();
    red[0][w][j] = s1; red[1][w][j] = s2; red[2][w][j] = qsum;
    __syncthreads();
    if (threadIdx.x < 64) {
        int idx = (b * 64 + l) * 64 + j;
        ws[WS_S1  + idx] = red[0][0][j] + red[0][1][j] + red[0][2][j] + red[0][3][j];
        ws[WS_S2P + idx] = red[1][0][j] + red[1][1][j] + red[1][2][j] + red[1][3][j];
        ws[WS_QSP + idx] = red[2][0][j] + red[2][1][j] + red[2][2][j] + red[2][3][j];
    }
}

__global__ __launch_bounds__(256) void kB(const float* __restrict__ X,
                                          float* __restrict__ ws) {
    int b = blockIdx.x >> 6;
    int h = blockIdx.x & 63;
    int w = threadIdx.x >> 6;
    int j = threadIdx.x & 63;
    float acc = 0.f, ps2 = 0.f, pqs = 0.f;
#pragma unroll
    for (int k = 0; k < 16; k++) {
        int l = w * 16 + k;
        float x = X[((size_t)(b * HW) + h * 64 + l) * 64 + j];
        int idx = (b * 64 + l) * 64 + j;
        acc = fmaf(x, ws[WS_S1 + idx], acc);
        ps2 += ws[WS_S2P + idx];
        pqs += ws[WS_QSP + idx];
    }
    __shared__ float ra[4][64], rb[4][64], rc[4][64];
    ra[w][j] = acc; rb[w][j] = ps2; rc[w][j] = pqs;
    __syncthreads();
    if (threadIdx.x < 64) {
        float a  = ra[0][j] + ra[1][j] + ra[2][j] + ra[3][j];
        float s2 = rb[0][j] + rb[1][j] + rb[2][j] + rb[3][j];
        float qs = rc[0][j] + rc[1][j] + rc[2][j] + rc[3][j];
        ws[WS_Z + (b * 64 + h) * 64 + j] = (a - s2 + EPSF) / (qs + EPSF);
    }
}

__global__ __launch_bounds__(256) void kC(const float* __restrict__ weight,
                                          float* __restrict__ ws) {
    int b = blockIdx.x >> 6;
    int v = blockIdx.x & 63;
    int w4 = threadIdx.x >> 6;
    int j = threadIdx.x & 63;
    __shared__ float gred[4][64], pred[4][64], nred[4][64];
    float gp = 0.f, pp = 0.f, np = 0.f;
#pragma unroll
    for (int k = 0; k < 16; k++) {
        int d = w4 * 16 + k;
        float zdj = ws[WS_Z + b * 4096 + d * 64 + j];
        float wdj = weight[d * 64 + j];
        float zdv = ws[WS_Z + b * 4096 + d * 64 + v];
        gp = fmaf(zdv, zdj, gp);
        pp = fmaf(zdv, wdj, pp);
        np = fmaf(zdj, zdj, np);
    }
    gred[w4][j] = gp; pred[w4][j] = pp; nred[w4][j] = np;
    __syncthreads();
    if (threadIdx.x < 64) {
        float G = gred[0][j] + gred[1][j] + gred[2][j] + gred[3][j];
        float P = pred[0][j] + pred[1][j] + pred[2][j] + pred[3][j];
        float N = nred[0][j] + nred[1][j] + nred[2][j] + nred[3][j];
        ws[WS_G + (b * 64 + v) * 64 + j] = G;
        ws[WS_P + (b * 64 + v) * 64 + j] = P;
        if (v == 0) {
            ws[WS_NRM + b * 64 + j] = N;
            ws[WS_IN2 + b * 64 + j] = 1.0f / (N * N);
        }
    }
}

__global__ __launch_bounds__(256) void kDl(float* __restrict__ ws) {
    int b = blockIdx.x >> 6;
    int v = blockIdx.x & 63;
    int w4 = threadIdx.x >> 6;
    int j = threadIdx.x & 63;
    __shared__ float ghat[64];
    __shared__ float red[4][64];
    if (threadIdx.x < 64)
        ghat[threadIdx.x] = ws[WS_G + (b * 64 + v) * 64 + threadIdx.x]
                          * ws[WS_IN2 + b * 64 + threadIdx.x];
    __syncthreads();
    float acc = 0.f;
#pragma unroll
    for (int k = 0; k < 16; k++) {
        int u = w4 * 16 + k;
        acc = fmaf(ghat[u], ws[WS_P + (b * 64 + u) * 64 + j], acc);
    }
    red[w4][j] = acc;
    __syncthreads();
    if (threadIdx.x < 64) {
        float r = (red[0][j] + red[1][j] + red[2][j] + red[3][j]) / ws[WS_NRM + b * 64 + v];
        r = r > 0.f ? r : 0.f;
        ws[WS_ZO + (b * 64 + v) * 64 + j] = r;
    }
}

__global__ __launch_bounds__(256) void kF(const float* __restrict__ ws,
                                          float* __restrict__ out) {
    int b = blockIdx.x >> 6;
    int tb = blockIdx.x & 63;
    int nbase = tb * 64;
    int w = threadIdx.x >> 6;
    int lane = threadIdx.x & 63;
    int w16 = w * 16;
    __shared__ float qs[64][65];
    __shared__ float zo[64][68];
#pragma unroll
    for (int k = 0; k < 16; k++) {
        int idx = threadIdx.x + 256 * k;
        int r = idx >> 6, cc = idx & 63;
        qs[r][cc] = ws[WS_Q + ((size_t)(b * HW) + nbase + r) * 64 + cc];
        zo[r][cc] = ws[WS_ZO + b * 4096 + idx];
    }
    __syncthreads();
    float acc[16];
#pragma unroll
    for (int k = 0; k < 16; k++) acc[k] = 0.f;
#pragma unroll
    for (int v = 0; v < 64; v++) {
        float qv = qs[lane][v];
        float4 z0 = *(const float4*)&zo[v][w16];
        float4 z1 = *(const float4*)&zo[v][w16 + 4];
        float4 z2 = *(const float4*)&zo[v][w16 + 8];
        float4 z3 = *(const float4*)&zo[v][w16 + 12];
        acc[0]  = fmaf(qv, z0.x, acc[0]);   acc[1]  = fmaf(qv, z0.y, acc[1]);
        acc[2]  = fmaf(qv, z0.z, acc[2]);   acc[3]  = fmaf(qv, z0.w, acc[3]);
        acc[4]  = fmaf(qv, z1.x, acc[4]);   acc[5]  = fmaf(qv, z1.y, acc[5]);
        acc[6]  = fmaf(qv, z1.z, acc[6]);   acc[7]  = fmaf(qv, z1.w, acc[7]);
        acc[8]  = fmaf(qv, z2.x, acc[8]);   acc[9]  = fmaf(qv, z2.y, acc[9]);
        acc[10] = fmaf(qv, z2.z, acc[10]);  acc[11] = fmaf(qv, z2.w, acc[11]);
        acc[12] = fmaf(qv, z3.x, acc[12]);  acc[13] = fmaf(qv, z3.y, acc[13]);
        acc[14] = fmaf(qv, z3.z, acc[14]);  acc[15] = fmaf(qv, z3.w, acc[15]);
    }
#pragma unroll
    for (int k = 0; k < 16; k++) {
        int o = w16 + k;
        out[(size_t)(b * 64 + o) * HW + nbase + lane] = acc[k];
    }
}

extern "C" void kernel_launch(void* const* d_in, const int* in_sizes, int n_in,
                              void* d_out, int out_size, void* d_ws, size_t ws_size,
                              hipStream_t stream) {
    const float* X      = (const float*)d_in[0];
    const float* Wm     = (const float*)d_in[1];
    const float* var    = (const float*)d_in[2];
    const float* weight = (const float*)d_in[3];
    float* ws  = (float*)d_ws;
    float* out = (float*)d_out;

    void* args[] = { (void*)&X, (void*)&Wm, (void*)&var, (void*)&weight,
                     (void*)&ws, (void*)&out };
    hipError_t err = hipLaunchCooperativeKernel((const void*)fused_all,
                                                dim3(256), dim3(256),
                                                args, 0, stream);
    if (err != hipSuccess) {
        // Fallback: proven 5-kernel path.
        kA <<<256, 256, 0, stream>>>(X, Wm, var, ws);
        kB <<<256, 256, 0, stream>>>(X, ws);
        kC <<<256, 256, 0, stream>>>(weight, ws);
        kDl<<<256, 256, 0, stream>>>(ws);
        kF <<<256, 256, 0, stream>>>(ws, out);
    }
}

// Round 5
// 21.511 us; speedup vs baseline: 10.8595x; 10.8595x over previous
//
#include <hip/hip_runtime.h>

// Problem constants: B=4, H=64, W=64, d=V=O=64, HW=4096
#define HW 4096
#define EPSF 1e-7f

// ws layout (float offsets):
#define WS_S1  0         // [4*64*64]  S1[b,l,j]
#define WS_S2P 16384     // [4*64*64]  S2 partial per l
#define WS_QSP 32768     // [4*64*64]  Qsum partial per l
#define WS_Z   49152     // [4*64*64]  z[b,h,j] (pre-norm)
#define WS_ZO  65536     // [4*64*64]  Zo (post-relu)
#define WS_Q   81920     // [4*4096*64] Q

// ---------------------------------------------------------------------------
// kA: grid 256 = (b,l), 512 threads (8 waves, 8 rows each).
// ABC constants + Q rows (stored) + S1/S2p/Qsp.
__global__ __launch_bounds__(512) void kA(const float* __restrict__ X,
                                          const float* __restrict__ Wm,
                                          const float* __restrict__ var,
                                          float* __restrict__ ws) {
    int b = blockIdx.x >> 6, l = blockIdx.x & 63;
    int w8 = threadIdx.x >> 6, j = threadIdx.x & 63;
    __shared__ float red[3][8][64];
    __shared__ float abc[3][64];
    float invr[8], wivr[8];
    float a = 0.f, bq = 0.f, c = 0.f;
#pragma unroll
    for (int k = 0; k < 8; k++) {
        int i = w8 * 8 + k;
        float v  = var[i * 64 + j];
        float wv = Wm[i * 64 + j];
        float iv = 1.0f / v;
        invr[k] = iv; wivr[k] = wv * iv;
        float iv2 = iv * iv;
        a += iv2; bq += wv * iv2; c += wv * wv * iv2;
    }
    red[0][w8][j] = a; red[1][w8][j] = bq; red[2][w8][j] = c;
    __syncthreads();
    if (threadIdx.x < 64) {
        float t0 = 0.f, t1 = 0.f, t2 = 0.f;
#pragma unroll
        for (int t = 0; t < 8; t++) { t0 += red[0][t][j]; t1 += red[1][t][j]; t2 += red[2][t][j]; }
        abc[0][j] = t0; abc[1][j] = t1; abc[2][j] = t2;
    }
    __syncthreads();
    float Aj = abc[0][j], Bj = abc[1][j], Cj = abc[2][j];

    float s1 = 0.f, s2 = 0.f, qsum = 0.f;
#pragma unroll
    for (int k = 0; k < 8; k++) {
        int i = w8 * 8 + k;
        int n = l * 64 + i;
        float x = X[((b * HW) + n) * 64 + j];
        float q = fmaf(fmaf(Aj, x, -2.0f * Bj), x, Cj);
        float m = q;
        for (int off = 1; off < 64; off <<= 1) m = fminf(m, __shfl_xor(m, off));
        float e = __expf(-0.5f * (q - m));
        float s = e;
        for (int off = 1; off < 64; off <<= 1) s += __shfl_xor(s, off);
        float Qv = e / s;
        ws[WS_Q + ((size_t)(b * HW) + n) * 64 + j] = Qv;
        s1 = fmaf(invr[k], Qv, s1);
        s2 = fmaf(wivr[k], Qv, s2);
        qsum += Qv;
    }
    __syncthreads();
    red[0][w8][j] = s1; red[1][w8][j] = s2; red[2][w8][j] = qsum;
    __syncthreads();
    if (threadIdx.x < 64) {
        float t0 = 0.f, t1 = 0.f, t2 = 0.f;
#pragma unroll
        for (int t = 0; t < 8; t++) { t0 += red[0][t][j]; t1 += red[1][t][j]; t2 += red[2][t][j]; }
        int idx = (b * 64 + l) * 64 + j;
        ws[WS_S1  + idx] = t0;
        ws[WS_S2P + idx] = t1;
        ws[WS_QSP + idx] = t2;
    }
}

// ---------------------------------------------------------------------------
// kB: grid 256 = (b,h), 512 threads. z[b,h,j].
__global__ __launch_bounds__(512) void kB(const float* __restrict__ X,
                                          float* __restrict__ ws) {
    int b = blockIdx.x >> 6, h = blockIdx.x & 63;
    int w8 = threadIdx.x >> 6, j = threadIdx.x & 63;
    float acc = 0.f, ps2 = 0.f, pqs = 0.f;
#pragma unroll
    for (int k = 0; k < 8; k++) {
        int l = w8 * 8 + k;
        float x = X[((size_t)(b * HW) + h * 64 + l) * 64 + j];
        int idx = (b * 64 + l) * 64 + j;
        acc = fmaf(x, ws[WS_S1 + idx], acc);
        ps2 += ws[WS_S2P + idx];
        pqs += ws[WS_QSP + idx];
    }
    __shared__ float ra[8][64], rb[8][64], rc[8][64];
    ra[w8][j] = acc; rb[w8][j] = ps2; rc[w8][j] = pqs;
    __syncthreads();
    if (threadIdx.x < 64) {
        float a = 0.f, s2 = 0.f, qs = 0.f;
#pragma unroll
        for (int t = 0; t < 8; t++) { a += ra[t][j]; s2 += rb[t][j]; qs += rc[t][j]; }
        ws[WS_Z + (b * 64 + h) * 64 + j] = (a - s2 + EPSF) / (qs + EPSF);
    }
}

// ---------------------------------------------------------------------------
// kCD: grid 256 = (b,v), 512 threads. Fused kC+kDl via:
//   Zo[v,o] = relu( (1/N[v]) * sum_d y[d]*w[d,o] ),
//   y[d] = sum_u ghat[u]*z[d,u],  ghat[u] = G[v,u]/N[u]^2,  G[v,u]=sum_d z[d,v]z[d,u]
__global__ __launch_bounds__(512) void kCD(const float* __restrict__ weight,
                                           float* __restrict__ ws) {
    int b = blockIdx.x >> 6, v = blockIdx.x & 63;
    int w8 = threadIdx.x >> 6, j = threadIdx.x & 63;
    __shared__ float zl[64][65];
    __shared__ float wl[64][65];
    __shared__ float red[8][64];
    __shared__ float sN[64], sin2[64], ghat[64], yv[64];
#pragma unroll
    for (int k = 0; k < 8; k++) {
        int idx = threadIdx.x + 512 * k;
        int r = idx >> 6, cc = idx & 63;
        zl[r][cc] = ws[WS_Z + b * 4096 + idx];
        wl[r][cc] = weight[idx];
    }
    __syncthreads();
    // N[j] = sum_d z[d,j]^2
    {
        float na = 0.f;
#pragma unroll
        for (int k = 0; k < 8; k++) { float zz = zl[w8 * 8 + k][j]; na = fmaf(zz, zz, na); }
        red[w8][j] = na;
        __syncthreads();
        if (threadIdx.x < 64) {
            float s = 0.f;
#pragma unroll
            for (int t = 0; t < 8; t++) s += red[t][j];
            sN[j] = s; sin2[j] = 1.0f / (s * s);
        }
        __syncthreads();
    }
    // ghat[u] = (sum_d z[d,v]*z[d,u]) * in2[u]
    {
        float g = 0.f;
#pragma unroll
        for (int k = 0; k < 8; k++) { int d = w8 * 8 + k; g = fmaf(zl[d][v], zl[d][j], g); }
        red[w8][j] = g;
        __syncthreads();
        if (threadIdx.x < 64) {
            float s = 0.f;
#pragma unroll
            for (int t = 0; t < 8; t++) s += red[t][j];
            ghat[j] = s * sin2[j];
        }
        __syncthreads();
    }
    // y[d] = sum_u ghat[u]*z[d,u]   (d = lane j; row read of zl is conflict-free)
    {
        float y = 0.f;
#pragma unroll
        for (int k = 0; k < 8; k++) { int u = w8 * 8 + k; y = fmaf(ghat[u], zl[j][u], y); }
        red[w8][j] = y;
        __syncthreads();
        if (threadIdx.x < 64) {
            float s = 0.f;
#pragma unroll
            for (int t = 0; t < 8; t++) s += red[t][j];
            yv[j] = s;
        }
        __syncthreads();
    }
    // Zo[v,o] = relu( (sum_d y[d]*w[d,o]) / N[v] )   (o = lane j)
    {
        float a = 0.f;
#pragma unroll
        for (int k = 0; k < 8; k++) { int d = w8 * 8 + k; a = fmaf(yv[d], wl[d][j], a); }
        red[w8][j] = a;
        __syncthreads();
        if (threadIdx.x < 64) {
            float s = 0.f;
#pragma unroll
            for (int t = 0; t < 8; t++) s += red[t][j];
            float r = s / sN[v];
            r = r > 0.f ? r : 0.f;
            ws[WS_ZO + (b * 64 + v) * 64 + j] = r;
        }
    }
}

// ---------------------------------------------------------------------------
// kF: grid 256 = (b, 64-row tile), 512 threads. out = Q * Zo, transposed write.
__global__ __launch_bounds__(512) void kF(const float* __restrict__ ws,
                                          float* __restrict__ out) {
    int b = blockIdx.x >> 6, tb = blockIdx.x & 63;
    int nbase = tb * 64;
    int w8 = threadIdx.x >> 6, lane = threadIdx.x & 63;
    int o8 = w8 * 8;
    __shared__ float qs[64][65];
    __shared__ float zo[64][68];   // row stride 272 B -> float4-aligned at o8 multiples of 8
#pragma unroll
    for (int k = 0; k < 8; k++) {
        int idx = threadIdx.x + 512 * k;
        int r = idx >> 6, cc = idx & 63;
        qs[r][cc] = ws[WS_Q + ((size_t)(b * HW) + nbase + r) * 64 + cc];
        zo[r][cc] = ws[WS_ZO + b * 4096 + idx];
    }
    __syncthreads();
    float acc[8];
#pragma unroll
    for (int k = 0; k < 8; k++) acc[k] = 0.f;
#pragma unroll
    for (int v = 0; v < 64; v++) {
        float qv = qs[lane][v];
        float4 z0 = *(const float4*)&zo[v][o8];
        float4 z1 = *(const float4*)&zo[v][o8 + 4];
        acc[0] = fmaf(qv, z0.x, acc[0]);
        acc[1] = fmaf(qv, z0.y, acc[1]);
        acc[2] = fmaf(qv, z0.z, acc[2]);
        acc[3] = fmaf(qv, z0.w, acc[3]);
        acc[4] = fmaf(qv, z1.x, acc[4]);
        acc[5] = fmaf(qv, z1.y, acc[5]);
        acc[6] = fmaf(qv, z1.z, acc[6]);
        acc[7] = fmaf(qv, z1.w, acc[7]);
    }
#pragma unroll
    for (int k = 0; k < 8; k++) {
        int o = o8 + k;
        out[(size_t)(b * 64 + o) * HW + nbase + lane] = acc[k];
    }
}

extern "C" void kernel_launch(void* const* d_in, const int* in_sizes, int n_in,
                              void* d_out, int out_size, void* d_ws, size_t ws_size,
                              hipStream_t stream) {
    const float* X      = (const float*)d_in[0];
    const float* Wm     = (const float*)d_in[1];
    const float* var    = (const float*)d_in[2];
    const float* weight = (const float*)d_in[3];
    float* ws  = (float*)d_ws;
    float* out = (float*)d_out;

    kA <<<256, 512, 0, stream>>>(X, Wm, var, ws);
    kB <<<256, 512, 0, stream>>>(X, ws);
    kCD<<<256, 512, 0, stream>>>(weight, ws);
    kF <<<256, 512, 0, stream>>>(ws, out);
}